// Round 21
// baseline (182.135 us; speedup 1.0000x reference)
//
#include <hip/hip_runtime.h>
#include <hip/hip_bf16.h>
#include <math.h>

typedef __attribute__((ext_vector_type(4))) float f32x4;
typedef __attribute__((ext_vector_type(16))) float f32x16;
typedef __attribute__((ext_vector_type(8))) short short8;
typedef __attribute__((ext_vector_type(4))) unsigned short ushort4_t;
typedef __attribute__((ext_vector_type(4))) unsigned int u32x4;

#define B_  4
#define S_  2048
#define D_  1024
#define NH_ 16
#define HD_ 64

__device__ __forceinline__ unsigned short f2bf(float f) {
  unsigned u = __builtin_bit_cast(unsigned, f);
  u += 0x7FFFu + ((u >> 16) & 1u);   // RNE
  return (unsigned short)(u >> 16);
}

__device__ __forceinline__ float bf2f(unsigned short s) {
  unsigned u = ((unsigned)s) << 16;
  return __builtin_bit_cast(float, u);
}

__device__ __forceinline__ float fexp2(float x) {
  float r;
  asm("v_exp_f32 %0, %1" : "=v"(r) : "v"(x));
  return r;
}

__device__ __forceinline__ void gload_lds16(const void* g, void* l) {
  __builtin_amdgcn_global_load_lds(
      (const __attribute__((address_space(1))) unsigned int*)g,
      (__attribute__((address_space(3))) unsigned int*)l, 16, 0, 0);
}

__device__ __forceinline__ unsigned cvt_pk_bf16(float lo, float hi) {
  unsigned r;
  asm("v_cvt_pk_bf16_f32 %0, %1, %2" : "=v"(r) : "v"(lo), "v"(hi));
  return r;
}

// ---------------- fp32 -> bf16 convert, all 7 arrays in one launch ----------
__global__ void cvt_bf16_all(
    const float* __restrict__ q, const float* __restrict__ k,
    const float* __restrict__ v, const float* __restrict__ wq,
    const float* __restrict__ wk, const float* __restrict__ wv,
    const float* __restrict__ wo,
    unsigned short* __restrict__ oq, unsigned short* __restrict__ ok,
    unsigned short* __restrict__ ov, unsigned short* __restrict__ owq,
    unsigned short* __restrict__ owk, unsigned short* __restrict__ owv,
    unsigned short* __restrict__ owo) {
  const int y = blockIdx.y;
  const float* in;
  unsigned short* out;
  int n4;
  switch (y) {
    case 0: in = q;  out = oq;  n4 = B_ * S_ * D_ / 4; break;
    case 1: in = k;  out = ok;  n4 = B_ * S_ * D_ / 4; break;
    case 2: in = v;  out = ov;  n4 = B_ * S_ * D_ / 4; break;
    case 3: in = wq; out = owq; n4 = 1024 * 1024 / 4;  break;
    case 4: in = wk; out = owk; n4 = 1024 * 1024 / 4;  break;
    case 5: in = wv; out = owv; n4 = 1024 * 1024 / 4;  break;
    default: in = wo; out = owo; n4 = 1024 * 1024 / 4; break;
  }
  for (int i = blockIdx.x * 256 + threadIdx.x; i < n4; i += 1024 * 256) {
    const float4 f = reinterpret_cast<const float4*>(in)[i];
    ushort4_t r;
    r.x = f2bf(f.x); r.y = f2bf(f.y); r.z = f2bf(f.z); r.w = f2bf(f.w);
    reinterpret_cast<ushort4_t*>(out)[i] = r;
  }
}

// ---- GEMM body (256x128 tile, dbuf, counted vmcnt, 512 thr, 8x 64x64) ----
// Per-wave 64x64 output: 4 A + 4 W ds_reads feed 16 MFMA per kk (ratio 2.0
// vs 1.33 of the 32x64 layout) -- cuts LDS-read bytes/FLOP 45->30, which is
// the measured bottleneck (96 KB/step vs 256 B/cyc >> MFMA time).
template <int OUT_F32>
__device__ __forceinline__ void gemm_body_db(
    const unsigned short* __restrict__ A,
    const unsigned short* __restrict__ W,
    const float* __restrict__ bias,
    void* __restrict__ Cout, int trans, float oscale,
    unsigned short* At, unsigned short* Wt, int m0, int n0) {
  constexpr int K = 1024;
  const int tid = threadIdx.x;
  const int wave = tid >> 6, lane = tid & 63;
  f32x4 acc[4][4] = {};

  const int srow = tid >> 3;     // 0..63
  const int scol8 = tid & 7;

  // staging source bases: A rows c*64+srow (c=0..3), W rows c*64+srow (c=0..1)
  const unsigned short* abase[4];
  const unsigned short* wbase[2];
#pragma unroll
  for (int c = 0; c < 4; ++c) {
    const int row = c * 64 + srow;
    const int col = (scol8 ^ (row & 7)) << 3;
    abase[c] = A + (size_t)(m0 + row) * K + col;
  }
#pragma unroll
  for (int c = 0; c < 2; ++c) {
    const int row = c * 64 + srow;
    const int col = (scol8 ^ (row & 7)) << 3;
    wbase[c] = W + (size_t)(n0 + row) * K + col;
  }

  auto STAGE = [&](int bi, int kt) {
#pragma unroll
    for (int c = 0; c < 4; ++c)
      gload_lds16(abase[c] + kt, (char*)At + bi * 32768 + c * 8192 + wave * 1024);
#pragma unroll
    for (int c = 0; c < 2; ++c)
      gload_lds16(wbase[c] + kt, (char*)Wt + bi * 16384 + c * 8192 + wave * 1024);
  };

  STAGE(0, 0);
  int cur = 0;
#pragma unroll 1
  for (int kt = 0; kt < K; kt += 64) {
    if (kt + 64 < K) {
      STAGE(cur ^ 1, kt + 64);
      asm volatile("s_waitcnt vmcnt(6)" ::: "memory");  // cur landed; next 6 in flight
    } else {
      asm volatile("s_waitcnt vmcnt(0)" ::: "memory");
    }
    __builtin_amdgcn_s_barrier();

    const char* AtC = (const char*)At + cur * 32768;
    const char* WtC = (const char*)Wt + cur * 16384;
    const int wr = (wave >> 1) * 64, wc = (wave & 1) * 64;
#pragma unroll
    for (int kk = 0; kk < 2; ++kk) {
      short8 af[4], wf[4];
#pragma unroll
      for (int m = 0; m < 4; ++m) {
        const int row = wr + m * 16 + (lane & 15);
        const int colb = ((kk * 32 + (lane >> 4) * 8) * 2) ^ ((row & 7) << 4);
        af[m] = *(const short8*)(AtC + row * 128 + colb);
      }
#pragma unroll
      for (int n = 0; n < 4; ++n) {
        const int row = wc + n * 16 + (lane & 15);
        const int colb = ((kk * 32 + (lane >> 4) * 8) * 2) ^ ((row & 7) << 4);
        wf[n] = *(const short8*)(WtC + row * 128 + colb);
      }
      __builtin_amdgcn_s_setprio(1);
#pragma unroll
      for (int m = 0; m < 4; ++m)
#pragma unroll
        for (int n = 0; n < 4; ++n)
          acc[m][n] = __builtin_amdgcn_mfma_f32_16x16x32_bf16(af[m], wf[n], acc[m][n], 0, 0, 0);
      __builtin_amdgcn_s_setprio(0);
    }
    __builtin_amdgcn_s_barrier();
    cur ^= 1;
  }

  const int wr = (wave >> 1) * 64, wc = (wave & 1) * 64;
  const int g = lane >> 4, cl = lane & 15;
#pragma unroll
  for (int m = 0; m < 4; ++m) {
#pragma unroll
    for (int n = 0; n < 4; ++n) {
      const int ng = n0 + wc + n * 16 + cl;
      const float bv = bias[ng];
      if (trans) {
        const int mg = m0 + wr + m * 16 + g * 4;
        const int bb = mg >> 11;
        const int ss = mg & 2047;
        ushort4_t pk;
        pk.x = f2bf(acc[m][n][0] + bv);
        pk.y = f2bf(acc[m][n][1] + bv);
        pk.z = f2bf(acc[m][n][2] + bv);
        pk.w = f2bf(acc[m][n][3] + bv);
        *(ushort4_t*)((unsigned short*)Cout + ((size_t)bb * 1024 + ng) * 2048 + ss) = pk;
      } else {
#pragma unroll
        for (int r = 0; r < 4; ++r) {
          const int mg = m0 + wr + m * 16 + g * 4 + r;
          const float v = (acc[m][n][r] + bv) * oscale;
          if (OUT_F32)
            ((float*)Cout)[(size_t)mg * 1024 + ng] = v;
          else
            ((unsigned short*)Cout)[(size_t)mg * 1024 + ng] = f2bf(v);
        }
      }
    }
  }
}

// fused Q/K/V projection, 256x128 tiles. XCD chunk = 768/8 = 96.
__global__ __launch_bounds__(512) void gemm_qkv(
    const unsigned short* __restrict__ qb, const unsigned short* __restrict__ kb,
    const unsigned short* __restrict__ vb,
    const unsigned short* __restrict__ Wqb, const unsigned short* __restrict__ Wkb,
    const unsigned short* __restrict__ Wvb,
    const float* __restrict__ bq, const float* __restrict__ bk,
    const float* __restrict__ bv,
    unsigned short* __restrict__ Qp, unsigned short* __restrict__ Kp,
    unsigned short* __restrict__ Vt) {
  __shared__ unsigned short At[2][256 * 64];
  __shared__ unsigned short Wt[2][128 * 64];
  const int fl = (int)blockIdx.x + 8 * (int)blockIdx.y + 256 * (int)blockIdx.z;
  const int o  = (fl & 7) * 96 + (fl >> 3);
  const int x = o & 7, y = (o >> 3) & 31, z = o >> 8;
  const unsigned short* A = z == 0 ? qb : (z == 1 ? kb : vb);
  const unsigned short* W = z == 0 ? Wqb : (z == 1 ? Wkb : Wvb);
  const float* bias = z == 0 ? bq : (z == 1 ? bk : bv);
  void* out = z == 0 ? (void*)Qp : (z == 1 ? (void*)Kp : (void*)Vt);
  const float sc = z == 0 ? 0.125f * 1.44269504088896f : 1.0f;
  gemm_body_db<0>(A, W, bias, out, z == 2, sc, &At[0][0], &Wt[0][0], y * 256, x * 128);
}

__global__ __launch_bounds__(512) void gemm_o(
    const unsigned short* __restrict__ A, const unsigned short* __restrict__ W,
    const float* __restrict__ bias, float* __restrict__ out) {
  __shared__ unsigned short At[2][256 * 64];
  __shared__ unsigned short Wt[2][128 * 64];
  const int fl = (int)blockIdx.x + 8 * (int)blockIdx.y;
  const int o  = (fl & 7) * 32 + (fl >> 3);
  const int x = o & 7, y = o >> 3;
  gemm_body_db<1>(A, W, bias, out, 0, 1.0f, &At[0][0], &Wt[0][0], y * 256, x * 128);
}

// ---------------- flash attention: swapped-QK^T 32x32, max-free softmax ------
// 512 threads / 8 waves share each staged K/V tile (256 q-rows per block).
// grid (4,64): 256 uniform blocks, q-tile pair {qx,7-qx} of 256 rows,
// 18 kv-iters each (KVBLK=128). XCD-chunked swizzle.
__global__ __launch_bounds__(512) void attn_fwd(
    const unsigned short* __restrict__ Qp,   // [B*S][1024], pre-scaled
    const unsigned short* __restrict__ Kp,   // [B*S][1024]
    const unsigned short* __restrict__ Vt,   // [B][1024][2048] (transposed)
    const unsigned char* __restrict__ pmask, // [B][2048]
    unsigned short* __restrict__ Out) {      // [8192][1024] bf16
  __shared__ unsigned short Kt[2][128 * 64];   // [kv 128][d 64], 128B rows
  __shared__ unsigned short Vl[2][64 * 128];   // [d 64][kv 128], 256B rows
  __shared__ unsigned char mskA[2048];

  const int tid = threadIdx.x;
  const int wave = tid >> 6, lane = tid & 63;
  const int ql = lane & 31, hi = lane >> 5;
  // XCD-chunked bijective swizzle (256 blocks, chunk 32)
  const int fl = (int)blockIdx.x + 4 * (int)blockIdx.y;
  const int o  = (fl & 7) * 32 + (fl >> 3);
  const int qx = o & 3, bh = o >> 2;
  const int b = bh >> 4, h = bh & 15;

  // stage padding mask for this batch into LDS once (4 B/thread x 512)
  *(unsigned*)(mskA + tid * 4) = *(const unsigned*)(pmask + b * S_ + tid * 4);
  asm volatile("s_waitcnt lgkmcnt(0)" ::: "memory");
  __builtin_amdgcn_s_barrier();

  // block-level anymask (each lane scans 32 bytes -> full 2048 per wave)
  bool anymask;
  {
    const u32x4 m0 = *(const u32x4*)(mskA + lane * 32);
    const u32x4 m1 = *(const u32x4*)(mskA + lane * 32 + 16);
    const unsigned orv = m0[0] | m0[1] | m0[2] | m0[3] | m1[0] | m1[1] | m1[2] | m1[3];
    anymask = __any(orv != 0);
  }

  // staging source bases (512 thr: 2 K + 2 V loads each).
  const unsigned short* kbase[2];
  const unsigned short* vbase[2];
#pragma unroll
  for (int c = 0; c < 2; ++c) {
    const int krow = c * 64 + (tid >> 3);
    const int kcol = ((tid & 7) ^ (krow & 7)) << 3;
    kbase[c] = Kp + (size_t)(b * S_ + krow) * D_ + h * HD_ + kcol;
    const int vrow = c * 32 + (tid >> 4);
    const int vcol = ((tid & 15) ^ (vrow & 15)) << 3;
    vbase[c] = Vt + ((size_t)b * D_ + h * HD_ + vrow) * S_ + vcol;
  }

#pragma unroll 1
  for (int half = 0; half < 2; ++half) {
    const int qtile = half ? (7 - qx) : qx;
    const int q0 = qtile * 256;
    const int qw = q0 + wave * 32;    // 8 waves cover 256 rows
    const int qg = qw + ql;           // this lane's q row
    const int nt = 2 * qtile + 2;     // kv tiles (128 wide)

    auto STAGE = [&](int bi, int t) {
      const size_t ko = (size_t)t * 128 * D_;
      const size_t vo = (size_t)t * 128;
#pragma unroll
      for (int c = 0; c < 2; ++c) {
        gload_lds16(kbase[c] + ko, (char*)Kt[bi] + c * 8192 + wave * 1024);
        gload_lds16(vbase[c] + vo, (char*)Vl[bi] + c * 8192 + wave * 1024);
      }
    };

    // Q B-fragments: col=q(ql), k = s*16 + hi*8 + j
    short8 qf[4];
#pragma unroll
    for (int s = 0; s < 4; ++s)
      qf[s] = *(const short8*)(Qp + (size_t)(b * S_ + qg) * D_ +
                               h * HD_ + s * 16 + hi * 8);

    float lrow = 0.f;                 // per-lane partial (this half of wave)
    f32x16 oacc[2] = {};

    STAGE(0, 0);
    int cur = 0;
#pragma unroll 1
    for (int t = 0; t < nt; ++t) {
      if (t + 1 < nt) {
        STAGE(cur ^ 1, t + 1);
        asm volatile("s_waitcnt vmcnt(4)" ::: "memory");  // cur landed; next in flight
      } else {
        asm volatile("s_waitcnt vmcnt(0)" ::: "memory");
      }
      __builtin_amdgcn_s_barrier();

      const char* KtC = (const char*)Kt[cur];
      const char* VlC = (const char*)Vl[cur];

#pragma unroll
      for (int j = 0; j < 2; ++j) {
        const int kvc = t * 128 + j * 64;
        if (kvc > qw + 31) continue;   // wave-uniform causal skip

        // S^T = K @ Q^T : st[tt] covers kv = kvc + tt*32 + crow(r,hi)
        f32x16 st[2] = {};
        __builtin_amdgcn_s_setprio(1);
#pragma unroll
        for (int tt = 0; tt < 2; ++tt) {
#pragma unroll
          for (int s = 0; s < 4; ++s) {
            const int row = j * 64 + tt * 32 + ql;
            const int colb = (s * 32 + hi * 16) ^ ((row & 7) << 4);
            const short8 kf = *(const short8*)(KtC + row * 128 + colb);
            st[tt] = __builtin_amdgcn_mfma_f32_32x32x16_bf16(kf, qf[s], st[tt], 0, 0, 0);
          }
        }
        __builtin_amdgcn_s_setprio(0);

        // padding mask (dead branch in this problem; anymask is block-uniform)
        if (anymask) {
#pragma unroll
          for (int tt = 0; tt < 2; ++tt)
#pragma unroll
            for (int r = 0; r < 16; ++r) {
              const int kv = kvc + tt * 32 + (r & 3) + 8 * (r >> 2) + 4 * hi;
              if (mskA[kv]) st[tt][r] = -1e30f;
            }
        }
        // causal mask (diagonal tiles only)
        if (kvc + 63 > qw) {
          const int kvb = kvc + 4 * hi;
#pragma unroll
          for (int tt = 0; tt < 2; ++tt)
#pragma unroll
            for (int r = 0; r < 16; ++r) {
              const int kv = kvb + tt * 32 + (r & 3) + 8 * (r >> 2);
              st[tt][r] = (kv > qg) ? -1e30f : st[tt][r];
            }
        }

        // P = exp2(s); 4 partial sums break the serial add chain.
        float rs0 = 0.f, rs1 = 0.f, rs2 = 0.f, rs3 = 0.f;
#pragma unroll
        for (int tt = 0; tt < 2; ++tt)
#pragma unroll
          for (int r = 0; r < 16; ++r) {
            const float p = fexp2(st[tt][r]);
            st[tt][r] = p;
            if ((r & 3) == 0) rs0 += p;
            else if ((r & 3) == 1) rs1 += p;
            else if ((r & 3) == 2) rs2 += p;
            else rs3 += p;
          }
        lrow += (rs0 + rs1) + (rs2 + rs3);

        // pack P -> PV A-fragments (cvt_pk + permlane32_swap)
        short8 pa[4];
#pragma unroll
        for (int tt = 0; tt < 2; ++tt) {
          unsigned c0 = cvt_pk_bf16(st[tt][0],  st[tt][1]);
          unsigned c1 = cvt_pk_bf16(st[tt][2],  st[tt][3]);
          unsigned c2 = cvt_pk_bf16(st[tt][4],  st[tt][5]);
          unsigned c3 = cvt_pk_bf16(st[tt][6],  st[tt][7]);
          unsigned c4 = cvt_pk_bf16(st[tt][8],  st[tt][9]);
          unsigned c5 = cvt_pk_bf16(st[tt][10], st[tt][11]);
          unsigned c6 = cvt_pk_bf16(st[tt][12], st[tt][13]);
          unsigned c7 = cvt_pk_bf16(st[tt][14], st[tt][15]);
          asm("v_permlane32_swap_b32 %0, %1" : "+v"(c0), "+v"(c2));
          asm("v_permlane32_swap_b32 %0, %1" : "+v"(c1), "+v"(c3));
          asm("v_permlane32_swap_b32 %0, %1" : "+v"(c4), "+v"(c6));
          asm("v_permlane32_swap_b32 %0, %1" : "+v"(c5), "+v"(c7));
          u32x4 w0 = {c0, c1, c2, c3};
          u32x4 w1 = {c4, c5, c6, c7};
          pa[2 * tt]     = __builtin_bit_cast(short8, w0);
          pa[2 * tt + 1] = __builtin_bit_cast(short8, w1);
        }

        // O += P @ V : oacc[dt] has d = dt*32 + ql, q = crow(r,hi)
        __builtin_amdgcn_s_setprio(1);
#pragma unroll
        for (int dt = 0; dt < 2; ++dt) {
#pragma unroll
          for (int ks = 0; ks < 4; ++ks) {
            const int vrow = dt * 32 + ql;
            const int vcolb = (j * 128 + ks * 32 + hi * 16) ^ ((vrow & 15) << 4);
            const short8 vf = *(const short8*)(VlC + vrow * 256 + vcolb);
            oacc[dt] = __builtin_amdgcn_mfma_f32_32x32x16_bf16(pa[ks], vf, oacc[dt], 0, 0, 0);
          }
        }
        __builtin_amdgcn_s_setprio(0);
      }
      __builtin_amdgcn_s_barrier();
      cur ^= 1;
    }

    // merge halves once, normalize + write: row q = qw + crow(r,hi)
    const float ltot = lrow + __shfl_xor(lrow, 32, 64);
    const float inv = 1.f / ltot;    // full row-sum for q = qw + ql
#pragma unroll
    for (int r = 0; r < 16; ++r) {
      const int crow = (r & 3) + 8 * (r >> 2) + 4 * hi;
      const float iv = __shfl(inv, crow, 64);
      const size_t base = (size_t)(b * S_ + qw + crow) * 1024 + h * HD_;
      Out[base + ql]      = f2bf(oacc[0][r] * iv);
      Out[base + 32 + ql] = f2bf(oacc[1][r] * iv);
    }
  }
}

// ---------------- launch ----------------
extern "C" void kernel_launch(void* const* d_in, const int* in_sizes, int n_in,
                              void* d_out, int out_size, void* d_ws, size_t ws_size,
                              hipStream_t stream) {
  (void)in_sizes; (void)n_in; (void)out_size; (void)ws_size;
  const float* q  = (const float*)d_in[0];
  const float* k  = (const float*)d_in[1];
  const float* v  = (const float*)d_in[2];
  const unsigned char* pm = (const unsigned char*)d_in[3];
  const float* Wq = (const float*)d_in[4];
  const float* bq = (const float*)d_in[5];
  const float* Wk = (const float*)d_in[6];
  const float* bk = (const float*)d_in[7];
  const float* Wv = (const float*)d_in[8];
  const float* bv = (const float*)d_in[9];
  const float* Wo = (const float*)d_in[10];
  const float* bo = (const float*)d_in[11];

  char* ws = (char*)d_ws;
  const size_t MB = 1024 * 1024;
  unsigned short* qb  = (unsigned short*)(ws + 0 * MB);
  unsigned short* kb  = (unsigned short*)(ws + 16 * MB);
  unsigned short* vb  = (unsigned short*)(ws + 32 * MB);
  unsigned short* Wqb = (unsigned short*)(ws + 48 * MB);
  unsigned short* Wkb = (unsigned short*)(ws + 50 * MB);
  unsigned short* Wvb = (unsigned short*)(ws + 52 * MB);
  unsigned short* Wob = (unsigned short*)(ws + 54 * MB);
  unsigned short* Qp  = (unsigned short*)(ws + 56 * MB);
  unsigned short* Kp  = (unsigned short*)(ws + 72 * MB);
  unsigned short* Vt  = (unsigned short*)(ws + 88 * MB);
  unsigned short* AO  = (unsigned short*)(ws + 104 * MB);

  cvt_bf16_all<<<dim3(1024, 7), dim3(256), 0, stream>>>(
      q, k, v, Wq, Wk, Wv, Wo, qb, kb, vb, Wqb, Wkb, Wvb, Wob);

  gemm_qkv<<<dim3(8, 32, 3), dim3(512), 0, stream>>>(qb, kb, vb, Wqb, Wkb, Wvb,
                                                     bq, bk, bv, Qp, Kp, Vt);

  attn_fwd<<<dim3(4, 64), dim3(512), 0, stream>>>(Qp, Kp, Vt, pm, AO);

  gemm_o<<<dim3(8, 32), dim3(512), 0, stream>>>(AO, Wob, bo, (float*)d_out);
}

// Round 22
// 160.187 us; speedup vs baseline: 1.1370x; 1.1370x over previous
//
#include <hip/hip_runtime.h>
#include <hip/hip_bf16.h>
#include <math.h>

typedef __attribute__((ext_vector_type(4))) float f32x4;
typedef __attribute__((ext_vector_type(16))) float f32x16;
typedef __attribute__((ext_vector_type(8))) short short8;
typedef __attribute__((ext_vector_type(4))) unsigned short ushort4_t;
typedef __attribute__((ext_vector_type(4))) unsigned int u32x4;

#define B_  4
#define S_  2048
#define D_  1024
#define NH_ 16
#define HD_ 64

__device__ __forceinline__ unsigned short f2bf(float f) {
  unsigned u = __builtin_bit_cast(unsigned, f);
  u += 0x7FFFu + ((u >> 16) & 1u);   // RNE
  return (unsigned short)(u >> 16);
}

__device__ __forceinline__ float bf2f(unsigned short s) {
  unsigned u = ((unsigned)s) << 16;
  return __builtin_bit_cast(float, u);
}

__device__ __forceinline__ float fexp2(float x) {
  float r;
  asm("v_exp_f32 %0, %1" : "=v"(r) : "v"(x));
  return r;
}

__device__ __forceinline__ void gload_lds16(const void* g, void* l) {
  __builtin_amdgcn_global_load_lds(
      (const __attribute__((address_space(1))) unsigned int*)g,
      (__attribute__((address_space(3))) unsigned int*)l, 16, 0, 0);
}

__device__ __forceinline__ unsigned cvt_pk_bf16(float lo, float hi) {
  unsigned r;
  asm("v_cvt_pk_bf16_f32 %0, %1, %2" : "=v"(r) : "v"(lo), "v"(hi));
  return r;
}

// ---------------- fp32 -> bf16 convert, all 7 arrays in one launch ----------
__global__ void cvt_bf16_all(
    const float* __restrict__ q, const float* __restrict__ k,
    const float* __restrict__ v, const float* __restrict__ wq,
    const float* __restrict__ wk, const float* __restrict__ wv,
    const float* __restrict__ wo,
    unsigned short* __restrict__ oq, unsigned short* __restrict__ ok,
    unsigned short* __restrict__ ov, unsigned short* __restrict__ owq,
    unsigned short* __restrict__ owk, unsigned short* __restrict__ owv,
    unsigned short* __restrict__ owo) {
  const int y = blockIdx.y;
  const float* in;
  unsigned short* out;
  int n4;
  switch (y) {
    case 0: in = q;  out = oq;  n4 = B_ * S_ * D_ / 4; break;
    case 1: in = k;  out = ok;  n4 = B_ * S_ * D_ / 4; break;
    case 2: in = v;  out = ov;  n4 = B_ * S_ * D_ / 4; break;
    case 3: in = wq; out = owq; n4 = 1024 * 1024 / 4;  break;
    case 4: in = wk; out = owk; n4 = 1024 * 1024 / 4;  break;
    case 5: in = wv; out = owv; n4 = 1024 * 1024 / 4;  break;
    default: in = wo; out = owo; n4 = 1024 * 1024 / 4; break;
  }
  for (int i = blockIdx.x * 256 + threadIdx.x; i < n4; i += 1024 * 256) {
    const float4 f = reinterpret_cast<const float4*>(in)[i];
    ushort4_t r;
    r.x = f2bf(f.x); r.y = f2bf(f.y); r.z = f2bf(f.z); r.w = f2bf(f.w);
    reinterpret_cast<ushort4_t*>(out)[i] = r;
  }
}

// ------- GEMM body (128x128 tile, dbuf, counted vmcnt, 512 threads) --------
// 8 waves x (32x64) sub-tiles: 2x4 16x16 fragments per wave (acc 32 VGPR).
// 4 waves/SIMD fills barrier/vmcnt idle slots (R19: 74->69us vs 256 thr).
// Ledger: 256-tile @256thr=105, @512thr=84 (1 blk/CU); 4-phase=87. This is
// the verified optimum of the 2-barrier family.
template <int OUT_F32>
__device__ __forceinline__ void gemm_body_db(
    const unsigned short* __restrict__ A,
    const unsigned short* __restrict__ W,
    const float* __restrict__ bias,
    void* __restrict__ Cout, int trans, float oscale,
    unsigned short* At, unsigned short* Wt, int m0, int n0) {
  constexpr int K = 1024;
  const int tid = threadIdx.x;
  const int wave = tid >> 6, lane = tid & 63;
  f32x4 acc[2][4] = {};

  const int srow = tid >> 3;     // 0..63
  const int scol8 = tid & 7;

  const unsigned short* abase[2];
  const unsigned short* wbase[2];
#pragma unroll
  for (int c = 0; c < 2; ++c) {
    const int row = c * 64 + srow;
    const int col = (scol8 ^ (row & 7)) << 3;
    abase[c] = A + (size_t)(m0 + row) * K + col;
    wbase[c] = W + (size_t)(n0 + row) * K + col;
  }

  auto STAGE = [&](int bi, int kt) {
#pragma unroll
    for (int c = 0; c < 2; ++c)
      gload_lds16(abase[c] + kt, (char*)At + bi * 16384 + c * 8192 + wave * 1024);
#pragma unroll
    for (int c = 0; c < 2; ++c)
      gload_lds16(wbase[c] + kt, (char*)Wt + bi * 16384 + c * 8192 + wave * 1024);
  };

  STAGE(0, 0);
  int cur = 0;
#pragma unroll 1
  for (int kt = 0; kt < K; kt += 64) {
    if (kt + 64 < K) {
      STAGE(cur ^ 1, kt + 64);
      asm volatile("s_waitcnt vmcnt(4)" ::: "memory");  // cur landed; next in flight
    } else {
      asm volatile("s_waitcnt vmcnt(0)" ::: "memory");
    }
    __builtin_amdgcn_s_barrier();

    const char* AtC = (const char*)At + cur * 16384;
    const char* WtC = (const char*)Wt + cur * 16384;
    const int wr = (wave >> 1) * 32, wc = (wave & 1) * 64;
#pragma unroll
    for (int kk = 0; kk < 2; ++kk) {
      short8 af[2], wf[4];
#pragma unroll
      for (int m = 0; m < 2; ++m) {
        const int row = wr + m * 16 + (lane & 15);
        const int colb = ((kk * 32 + (lane >> 4) * 8) * 2) ^ ((row & 7) << 4);
        af[m] = *(const short8*)(AtC + row * 128 + colb);
      }
#pragma unroll
      for (int n = 0; n < 4; ++n) {
        const int row = wc + n * 16 + (lane & 15);
        const int colb = ((kk * 32 + (lane >> 4) * 8) * 2) ^ ((row & 7) << 4);
        wf[n] = *(const short8*)(WtC + row * 128 + colb);
      }
      __builtin_amdgcn_s_setprio(1);
#pragma unroll
      for (int m = 0; m < 2; ++m)
#pragma unroll
        for (int n = 0; n < 4; ++n)
          acc[m][n] = __builtin_amdgcn_mfma_f32_16x16x32_bf16(af[m], wf[n], acc[m][n], 0, 0, 0);
      __builtin_amdgcn_s_setprio(0);
    }
    __builtin_amdgcn_s_barrier();
    cur ^= 1;
  }

  const int wr = (wave >> 1) * 32, wc = (wave & 1) * 64;
  const int g = lane >> 4, cl = lane & 15;
#pragma unroll
  for (int m = 0; m < 2; ++m) {
#pragma unroll
    for (int n = 0; n < 4; ++n) {
      const int ng = n0 + wc + n * 16 + cl;
      const float bv = bias[ng];
      if (trans) {
        const int mg = m0 + wr + m * 16 + g * 4;
        const int bb = mg >> 11;
        const int ss = mg & 2047;
        ushort4_t pk;
        pk.x = f2bf(acc[m][n][0] + bv);
        pk.y = f2bf(acc[m][n][1] + bv);
        pk.z = f2bf(acc[m][n][2] + bv);
        pk.w = f2bf(acc[m][n][3] + bv);
        *(ushort4_t*)((unsigned short*)Cout + ((size_t)bb * 1024 + ng) * 2048 + ss) = pk;
      } else {
#pragma unroll
        for (int r = 0; r < 4; ++r) {
          const int mg = m0 + wr + m * 16 + g * 4 + r;
          const float v = (acc[m][n][r] + bv) * oscale;
          if (OUT_F32)
            ((float*)Cout)[(size_t)mg * 1024 + ng] = v;
          else
            ((unsigned short*)Cout)[(size_t)mg * 1024 + ng] = f2bf(v);
        }
      }
    }
  }
}

// fused Q/K/V projection. XCD-chunked swizzle (chunk = 1536/8 = 192).
__global__ __launch_bounds__(512) void gemm_qkv(
    const unsigned short* __restrict__ qb, const unsigned short* __restrict__ kb,
    const unsigned short* __restrict__ vb,
    const unsigned short* __restrict__ Wqb, const unsigned short* __restrict__ Wkb,
    const unsigned short* __restrict__ Wvb,
    const float* __restrict__ bq, const float* __restrict__ bk,
    const float* __restrict__ bv,
    unsigned short* __restrict__ Qp, unsigned short* __restrict__ Kp,
    unsigned short* __restrict__ Vt) {
  __shared__ unsigned short At[2][128 * 64];
  __shared__ unsigned short Wt[2][128 * 64];
  const int fl = (int)blockIdx.x + 8 * (int)blockIdx.y + 512 * (int)blockIdx.z;
  const int o  = (fl & 7) * 192 + (fl >> 3);
  const int x = o & 7, y = (o >> 3) & 63, z = o >> 9;
  const unsigned short* A = z == 0 ? qb : (z == 1 ? kb : vb);
  const unsigned short* W = z == 0 ? Wqb : (z == 1 ? Wkb : Wvb);
  const float* bias = z == 0 ? bq : (z == 1 ? bk : bv);
  void* out = z == 0 ? (void*)Qp : (z == 1 ? (void*)Kp : (void*)Vt);
  const float sc = z == 0 ? 0.125f * 1.44269504088896f : 1.0f;
  gemm_body_db<0>(A, W, bias, out, z == 2, sc, &At[0][0], &Wt[0][0], y * 128, x * 128);
}

__global__ __launch_bounds__(512) void gemm_o(
    const unsigned short* __restrict__ A, const unsigned short* __restrict__ W,
    const float* __restrict__ bias, float* __restrict__ out) {
  __shared__ unsigned short At[2][128 * 64];
  __shared__ unsigned short Wt[2][128 * 64];
  const int fl = (int)blockIdx.x + 8 * (int)blockIdx.y;
  const int o  = (fl & 7) * 64 + (fl >> 3);
  const int x = o & 7, y = o >> 3;
  gemm_body_db<1>(A, W, bias, out, 0, 1.0f, &At[0][0], &Wt[0][0], y * 128, x * 128);
}

// ---------------- flash attention: swapped-QK^T 32x32, max-free softmax ------
// 512 threads / 8 waves share each staged K/V tile (256 q-rows per block).
// grid (4,64): 256 uniform blocks, q-tile pair {qx,7-qx} of 256 rows,
// 18 kv-iters each (KVBLK=128). Halves staging traffic vs 4-wave blocks.
__global__ __launch_bounds__(512) void attn_fwd(
    const unsigned short* __restrict__ Qp,   // [B*S][1024], pre-scaled
    const unsigned short* __restrict__ Kp,   // [B*S][1024]
    const unsigned short* __restrict__ Vt,   // [B][1024][2048] (transposed)
    const unsigned char* __restrict__ pmask, // [B][2048]
    unsigned short* __restrict__ Out) {      // [8192][1024] bf16
  __shared__ unsigned short Kt[2][128 * 64];   // [kv 128][d 64], 128B rows
  __shared__ unsigned short Vl[2][64 * 128];   // [d 64][kv 128], 256B rows
  __shared__ unsigned char mskA[2048];

  const int tid = threadIdx.x;
  const int wave = tid >> 6, lane = tid & 63;
  const int ql = lane & 31, hi = lane >> 5;
  // XCD-chunked bijective swizzle (256 blocks, chunk 32)
  const int fl = (int)blockIdx.x + 4 * (int)blockIdx.y;
  const int o  = (fl & 7) * 32 + (fl >> 3);
  const int qx = o & 3, bh = o >> 2;
  const int b = bh >> 4, h = bh & 15;

  // stage padding mask for this batch into LDS once (4 B/thread x 512)
  *(unsigned*)(mskA + tid * 4) = *(const unsigned*)(pmask + b * S_ + tid * 4);
  asm volatile("s_waitcnt lgkmcnt(0)" ::: "memory");
  __builtin_amdgcn_s_barrier();

  // block-level anymask (each lane scans 32 bytes -> full 2048 per wave)
  bool anymask;
  {
    const u32x4 m0 = *(const u32x4*)(mskA + lane * 32);
    const u32x4 m1 = *(const u32x4*)(mskA + lane * 32 + 16);
    const unsigned orv = m0[0] | m0[1] | m0[2] | m0[3] | m1[0] | m1[1] | m1[2] | m1[3];
    anymask = __any(orv != 0);
  }

  // staging source bases (512 thr: 2 K + 2 V loads each).
  // K: row = c*64 + tid>>3, slot tid&7, swz8. V: row = c*32 + tid>>4, swz16.
  const unsigned short* kbase[2];
  const unsigned short* vbase[2];
#pragma unroll
  for (int c = 0; c < 2; ++c) {
    const int krow = c * 64 + (tid >> 3);
    const int kcol = ((tid & 7) ^ (krow & 7)) << 3;
    kbase[c] = Kp + (size_t)(b * S_ + krow) * D_ + h * HD_ + kcol;
    const int vrow = c * 32 + (tid >> 4);
    const int vcol = ((tid & 15) ^ (vrow & 15)) << 3;
    vbase[c] = Vt + ((size_t)b * D_ + h * HD_ + vrow) * S_ + vcol;
  }

#pragma unroll 1
  for (int half = 0; half < 2; ++half) {
    const int qtile = half ? (7 - qx) : qx;
    const int q0 = qtile * 256;
    const int qw = q0 + wave * 32;    // 8 waves cover 256 rows
    const int qg = qw + ql;           // this lane's q row
    const int nt = 2 * qtile + 2;     // kv tiles (128 wide)

    auto STAGE = [&](int bi, int t) {
      const size_t ko = (size_t)t * 128 * D_;
      const size_t vo = (size_t)t * 128;
#pragma unroll
      for (int c = 0; c < 2; ++c) {
        gload_lds16(kbase[c] + ko, (char*)Kt[bi] + c * 8192 + wave * 1024);
        gload_lds16(vbase[c] + vo, (char*)Vl[bi] + c * 8192 + wave * 1024);
      }
    };

    // Q B-fragments: col=q(ql), k = s*16 + hi*8 + j
    short8 qf[4];
#pragma unroll
    for (int s = 0; s < 4; ++s)
      qf[s] = *(const short8*)(Qp + (size_t)(b * S_ + qg) * D_ +
                               h * HD_ + s * 16 + hi * 8);

    float lrow = 0.f;                 // per-lane partial (this half of wave)
    f32x16 oacc[2] = {};

    STAGE(0, 0);
    int cur = 0;
#pragma unroll 1
    for (int t = 0; t < nt; ++t) {
      if (t + 1 < nt) {
        STAGE(cur ^ 1, t + 1);
        asm volatile("s_waitcnt vmcnt(4)" ::: "memory");  // cur landed; next in flight
      } else {
        asm volatile("s_waitcnt vmcnt(0)" ::: "memory");
      }
      __builtin_amdgcn_s_barrier();

      const char* KtC = (const char*)Kt[cur];
      const char* VlC = (const char*)Vl[cur];

#pragma unroll
      for (int j = 0; j < 2; ++j) {
        const int kvc = t * 128 + j * 64;
        if (kvc > qw + 31) continue;   // wave-uniform causal skip

        // S^T = K @ Q^T : st[tt] covers kv = kvc + tt*32 + crow(r,hi)
        f32x16 st[2] = {};
        __builtin_amdgcn_s_setprio(1);
#pragma unroll
        for (int tt = 0; tt < 2; ++tt) {
#pragma unroll
          for (int s = 0; s < 4; ++s) {
            const int row = j * 64 + tt * 32 + ql;
            const int colb = (s * 32 + hi * 16) ^ ((row & 7) << 4);
            const short8 kf = *(const short8*)(KtC + row * 128 + colb);
            st[tt] = __builtin_amdgcn_mfma_f32_32x32x16_bf16(kf, qf[s], st[tt], 0, 0, 0);
          }
        }
        __builtin_amdgcn_s_setprio(0);

        // padding mask (dead branch in this problem; anymask is block-uniform)
        if (anymask) {
#pragma unroll
          for (int tt = 0; tt < 2; ++tt)
#pragma unroll
            for (int r = 0; r < 16; ++r) {
              const int kv = kvc + tt * 32 + (r & 3) + 8 * (r >> 2) + 4 * hi;
              if (mskA[kv]) st[tt][r] = -1e30f;
            }
        }
        // causal mask (diagonal tiles only)
        if (kvc + 63 > qw) {
          const int kvb = kvc + 4 * hi;
#pragma unroll
          for (int tt = 0; tt < 2; ++tt)
#pragma unroll
            for (int r = 0; r < 16; ++r) {
              const int kv = kvb + tt * 32 + (r & 3) + 8 * (r >> 2);
              st[tt][r] = (kv > qg) ? -1e30f : st[tt][r];
            }
        }

        // P = exp2(s); 4 partial sums break the serial add chain.
        float rs0 = 0.f, rs1 = 0.f, rs2 = 0.f, rs3 = 0.f;
#pragma unroll
        for (int tt = 0; tt < 2; ++tt)
#pragma unroll
          for (int r = 0; r < 16; ++r) {
            const float p = fexp2(st[tt][r]);
            st[tt][r] = p;
            if ((r & 3) == 0) rs0 += p;
            else if ((r & 3) == 1) rs1 += p;
            else if ((r & 3) == 2) rs2 += p;
            else rs3 += p;
          }
        lrow += (rs0 + rs1) + (rs2 + rs3);

        // pack P -> PV A-fragments (cvt_pk + permlane32_swap)
        short8 pa[4];
#pragma unroll
        for (int tt = 0; tt < 2; ++tt) {
          unsigned c0 = cvt_pk_bf16(st[tt][0],  st[tt][1]);
          unsigned c1 = cvt_pk_bf16(st[tt][2],  st[tt][3]);
          unsigned c2 = cvt_pk_bf16(st[tt][4],  st[tt][5]);
          unsigned c3 = cvt_pk_bf16(st[tt][6],  st[tt][7]);
          unsigned c4 = cvt_pk_bf16(st[tt][8],  st[tt][9]);
          unsigned c5 = cvt_pk_bf16(st[tt][10], st[tt][11]);
          unsigned c6 = cvt_pk_bf16(st[tt][12], st[tt][13]);
          unsigned c7 = cvt_pk_bf16(st[tt][14], st[tt][15]);
          asm("v_permlane32_swap_b32 %0, %1" : "+v"(c0), "+v"(c2));
          asm("v_permlane32_swap_b32 %0, %1" : "+v"(c1), "+v"(c3));
          asm("v_permlane32_swap_b32 %0, %1" : "+v"(c4), "+v"(c6));
          asm("v_permlane32_swap_b32 %0, %1" : "+v"(c5), "+v"(c7));
          u32x4 w0 = {c0, c1, c2, c3};
          u32x4 w1 = {c4, c5, c6, c7};
          pa[2 * tt]     = __builtin_bit_cast(short8, w0);
          pa[2 * tt + 1] = __builtin_bit_cast(short8, w1);
        }

        // O += P @ V : oacc[dt] has d = dt*32 + ql, q = crow(r,hi)
        __builtin_amdgcn_s_setprio(1);
#pragma unroll
        for (int dt = 0; dt < 2; ++dt) {
#pragma unroll
          for (int ks = 0; ks < 4; ++ks) {
            const int vrow = dt * 32 + ql;
            const int vcolb = (j * 128 + ks * 32 + hi * 16) ^ ((vrow & 15) << 4);
            const short8 vf = *(const short8*)(VlC + vrow * 256 + vcolb);
            oacc[dt] = __builtin_amdgcn_mfma_f32_32x32x16_bf16(pa[ks], vf, oacc[dt], 0, 0, 0);
          }
        }
        __builtin_amdgcn_s_setprio(0);
      }
      __builtin_amdgcn_s_barrier();
      cur ^= 1;
    }

    // merge halves once, normalize + write: row q = qw + crow(r,hi)
    const float ltot = lrow + __shfl_xor(lrow, 32, 64);
    const float inv = 1.f / ltot;    // full row-sum for q = qw + ql
#pragma unroll
    for (int r = 0; r < 16; ++r) {
      const int crow = (r & 3) + 8 * (r >> 2) + 4 * hi;
      const float iv = __shfl(inv, crow, 64);
      const size_t base = (size_t)(b * S_ + qw + crow) * 1024 + h * HD_;
      Out[base + ql]      = f2bf(oacc[0][r] * iv);
      Out[base + 32 + ql] = f2bf(oacc[1][r] * iv);
    }
  }
}

// ---------------- launch ----------------
extern "C" void kernel_launch(void* const* d_in, const int* in_sizes, int n_in,
                              void* d_out, int out_size, void* d_ws, size_t ws_size,
                              hipStream_t stream) {
  (void)in_sizes; (void)n_in; (void)out_size; (void)ws_size;
  const float* q  = (const float*)d_in[0];
  const float* k  = (const float*)d_in[1];
  const float* v  = (const float*)d_in[2];
  const unsigned char* pm = (const unsigned char*)d_in[3];
  const float* Wq = (const float*)d_in[4];
  const float* bq = (const float*)d_in[5];
  const float* Wk = (const float*)d_in[6];
  const float* bk = (const float*)d_in[7];
  const float* Wv = (const float*)d_in[8];
  const float* bv = (const float*)d_in[9];
  const float* Wo = (const float*)d_in[10];
  const float* bo = (const float*)d_in[11];

  char* ws = (char*)d_ws;
  const size_t MB = 1024 * 1024;
  unsigned short* qb  = (unsigned short*)(ws + 0 * MB);
  unsigned short* kb  = (unsigned short*)(ws + 16 * MB);
  unsigned short* vb  = (unsigned short*)(ws + 32 * MB);
  unsigned short* Wqb = (unsigned short*)(ws + 48 * MB);
  unsigned short* Wkb = (unsigned short*)(ws + 50 * MB);
  unsigned short* Wvb = (unsigned short*)(ws + 52 * MB);
  unsigned short* Wob = (unsigned short*)(ws + 54 * MB);
  unsigned short* Qp  = (unsigned short*)(ws + 56 * MB);
  unsigned short* Kp  = (unsigned short*)(ws + 72 * MB);
  unsigned short* Vt  = (unsigned short*)(ws + 88 * MB);
  unsigned short* AO  = (unsigned short*)(ws + 104 * MB);

  cvt_bf16_all<<<dim3(1024, 7), dim3(256), 0, stream>>>(
      q, k, v, Wq, Wk, Wv, Wo, qb, kb, vb, Wqb, Wkb, Wvb, Wob);

  gemm_qkv<<<dim3(8, 64, 3), dim3(512), 0, stream>>>(qb, kb, vb, Wqb, Wkb, Wvb,
                                                     bq, bk, bv, Qp, Kp, Vt);

  attn_fwd<<<dim3(4, 64), dim3(512), 0, stream>>>(Qp, Kp, Vt, pm, AO);

  gemm_o<<<dim3(8, 64), dim3(512), 0, stream>>>(AO, Wob, bo, (float*)d_out);
}